// Round 1
// baseline (14516.341 us; speedup 1.0000x reference)
//
#include <hip/hip_runtime.h>
#include <hip/hip_bf16.h>
#include <hip/hip_fp16.h>

#define TT 2048
#define BB 64
#define HH 512
#define GG 2048  // 4H

typedef __attribute__((ext_vector_type(4))) float f32x4;
typedef __attribute__((ext_vector_type(8))) short short8;
typedef __attribute__((ext_vector_type(4))) short short4v;

static __device__ __forceinline__ short f2bf(float f) {
  unsigned u = __builtin_bit_cast(unsigned, f);
  u = (u + 0x7FFFu + ((u >> 16) & 1u)) >> 16;
  return (short)u;
}
static __device__ __forceinline__ float fsigmoid(float x) {
  return 1.0f / (1.0f + __expf(-x));
}
static __device__ __forceinline__ float ftanh(float x) {
  float e = __expf(2.0f * x);
  return 1.0f - 2.0f / (e + 1.0f);
}

// ---------------- fp32 -> bf16 convert (vectorized, grid-stride) ----------------
__global__ void cvt_bf16_kernel(const float4* __restrict__ in, short4v* __restrict__ outp, long n4) {
  long i = (long)blockIdx.x * blockDim.x + threadIdx.x;
  long stride = (long)gridDim.x * blockDim.x;
  for (; i < n4; i += stride) {
    float4 v = in[i];
    short4v o;
    o[0] = f2bf(v.x); o[1] = f2bf(v.y); o[2] = f2bf(v.z); o[3] = f2bf(v.w);
    outp[i] = o;
  }
}

// ---------------- phase 1: xpart = X @ W_ih^T + (b_ih + b_hh) ----------------
// A: [131072][512] bf16, B: W_ih [2048][512] bf16 (B^T layout), out [131072][2048]
template <typename XT>
__global__ __launch_bounds__(256) void gemm_xpart(
    const __hip_bfloat16* __restrict__ Abf, const __hip_bfloat16* __restrict__ Bbf,
    const float* __restrict__ bih, const float* __restrict__ bhh, XT* __restrict__ xout) {
  __shared__ __hip_bfloat16 As[128 * 64];
  __shared__ __hip_bfloat16 Bs[128 * 64];
  const int nwg = gridDim.x;
  const int bid = blockIdx.x;
  const int vb = (bid & 7) * (nwg >> 3) + (bid >> 3);  // bijective XCD swizzle (nwg%8==0)
  const int mt = vb >> 4;
  const int nt = vb & 15;
  const size_t m0 = (size_t)mt * 128;
  const int n0 = nt * 128;
  const int tid = threadIdx.x;
  const int lane = tid & 63;
  const int w = tid >> 6;
  const int wm = w >> 1, wn = w & 1;
  const int g = lane >> 4;
  f32x4 acc[4][4] = {};
  for (int k0 = 0; k0 < 512; k0 += 64) {
#pragma unroll
    for (int i = 0; i < 4; i++) {
      const int slot = w * 4 + i;
      const int row = slot * 8 + (lane >> 3);
      const int segS = (lane & 7) ^ (row & 7);  // pre-swizzled global source (linear LDS dest)
      const __hip_bfloat16* ga = Abf + (m0 + row) * 512 + k0 + segS * 8;
      const __hip_bfloat16* gb = Bbf + (size_t)(n0 + row) * 512 + k0 + segS * 8;
      __builtin_amdgcn_global_load_lds(
          (const __attribute__((address_space(1))) unsigned*)(const void*)ga,
          (__attribute__((address_space(3))) unsigned*)(void*)(As + slot * 512), 16, 0, 0);
      __builtin_amdgcn_global_load_lds(
          (const __attribute__((address_space(1))) unsigned*)(const void*)gb,
          (__attribute__((address_space(3))) unsigned*)(void*)(Bs + slot * 512), 16, 0, 0);
    }
    __syncthreads();
#pragma unroll
    for (int kk = 0; kk < 2; kk++) {
      short8 av[4], bv[4];
#pragma unroll
      for (int f = 0; f < 4; f++) {
        const int row = wm * 64 + f * 16 + (lane & 15);
        av[f] = *(const short8*)(As + row * 64 + ((((kk << 2) + g) ^ (row & 7)) << 3));
      }
#pragma unroll
      for (int f = 0; f < 4; f++) {
        const int row = wn * 64 + f * 16 + (lane & 15);
        bv[f] = *(const short8*)(Bs + row * 64 + ((((kk << 2) + g) ^ (row & 7)) << 3));
      }
#pragma unroll
      for (int fi = 0; fi < 4; fi++)
#pragma unroll
        for (int fj = 0; fj < 4; fj++)
          acc[fi][fj] = __builtin_amdgcn_mfma_f32_16x16x32_bf16(av[fi], bv[fj], acc[fi][fj], 0, 0, 0);
    }
    __syncthreads();
  }
#pragma unroll
  for (int fj = 0; fj < 4; fj++) {
    const int n = n0 + wn * 64 + fj * 16 + (lane & 15);
    const float bias = bih[n] + bhh[n];
#pragma unroll
    for (int fi = 0; fi < 4; fi++) {
      const size_t mrow = m0 + wm * 64 + fi * 16 + g * 4;
#pragma unroll
      for (int r = 0; r < 4; r++) {
        const float vv = acc[fi][fj][r] + bias;
        if constexpr (sizeof(XT) == 4) xout[(mrow + r) * GG + n] = vv;
        else xout[(mrow + r) * GG + n] = __float2half(vv);
      }
    }
  }
}

// ---------------- phase 2: persistent LSTM scan ----------------
// 64 blocks x 256 threads. Block owns 8 h-columns (32 gate rows).
// gates^T[32x64] = Wslice[32x512] @ h^T[512x64]; wave w handles batch tile 16w..16w+15.
template <typename XT>
__global__ __launch_bounds__(256) void lstm_scan_kernel(
    const XT* __restrict__ xpart, const float* __restrict__ Whh,
    __hip_bfloat16* hbuf, float* __restrict__ outp, unsigned* __restrict__ flags) {
  __shared__ __hip_bfloat16 Wl[32 * 512];   // swizzled bf16 W_hh slice
  __shared__ float xps[2][64 * 36];         // xpart tile double-buffer (+pad for banks)
  const int blk = blockIdx.x;
  const int tid = threadIdx.x;
  const int lane = tid & 63;
  const int w = tid >> 6;

  // load + convert W_hh slice. Row order: r<16 -> (hc=2*(r>>2), q=r&3); r>=16 -> (hc=2*((r-16)>>2)+1, q=r&3)
  {
    const int r = tid >> 3;
    const int cs = tid & 7;
    const int q = r & 3;
    const int hc = (r < 16) ? ((r >> 2) << 1) : ((((r - 16) >> 2) << 1) | 1);
    const int grow = q * 512 + blk * 8 + hc;
    const float* src = Whh + (size_t)grow * 512 + cs * 64;
#pragma unroll
    for (int p = 0; p < 8; p++) {
      float4 u0 = *(const float4*)(src + p * 8);
      float4 u1 = *(const float4*)(src + p * 8 + 4);
      short8 v;
      v[0] = f2bf(u0.x); v[1] = f2bf(u0.y); v[2] = f2bf(u0.z); v[3] = f2bf(u0.w);
      v[4] = f2bf(u1.x); v[5] = f2bf(u1.y); v[6] = f2bf(u1.z); v[7] = f2bf(u1.w);
      const int s = cs * 8 + p;
      *(short8*)(Wl + r * 512 + ((s ^ (r & 7)) << 3)) = v;
    }
  }
  const int xrow = tid >> 2;
  const int xq = tid & 3;
  const int b16 = lane & 15;
  const int g4 = lane >> 4;
  const int batch = w * 16 + b16;
  const int hc0 = g4 << 1;
  const int col = blk * 8 + hc0;
  float c0 = 0.f, c1 = 0.f, h0 = 0.f, h1 = 0.f;

  {  // prefetch xpart tile t=0
    const XT* xsrc = xpart + (size_t)xrow * GG + xq * 512 + blk * 8;
    float* dst = &xps[0][xrow * 36 + xq * 8];
    if constexpr (sizeof(XT) == 4) {
      *(float4*)dst = *(const float4*)(const void*)xsrc;
      *(float4*)(dst + 4) = *(const float4*)(const void*)(xsrc + 4);
    } else {
      short8 ph0 = *(const short8*)(const void*)xsrc;
#pragma unroll
      for (int j = 0; j < 8; j++) {
        union { unsigned short u; __half h; } cvu; cvu.u = (unsigned short)ph0[j];
        dst[j] = __half2float(cvu.h);
      }
    }
  }
  __syncthreads();

  for (int t = 0; t < TT; t++) {
    // 1. issue next-step xpart loads (latency hides under sync+MFMA)
    const int tn = (t + 1 < TT) ? (t + 1) : (TT - 1);
    const XT* xsrc = xpart + ((size_t)tn * BB + xrow) * GG + xq * 512 + blk * 8;
    float4 pf0, pf1;
    short8 ph;
    if constexpr (sizeof(XT) == 4) {
      pf0 = *(const float4*)(const void*)xsrc;
      pf1 = *(const float4*)(const void*)(xsrc + 4);
    } else {
      ph = *(const short8*)(const void*)xsrc;
    }
    // 2. wait for h_t from all 64 blocks (acquire)
    if (t > 0) {
      if (w == 0) {
        while (true) {
          unsigned v = __hip_atomic_load(flags + lane, __ATOMIC_ACQUIRE, __HIP_MEMORY_SCOPE_AGENT);
          if (__all((int)(v >= (unsigned)t))) break;
        }
      }
      __syncthreads();
    }
    // 3. MFMA: gates^T slice
    const __hip_bfloat16* hsrc = hbuf + (size_t)(t & 1) * (BB * HH) + (size_t)batch * HH + g4 * 8;
    short8 bfr[16];
#pragma unroll
    for (int kt = 0; kt < 16; kt++) bfr[kt] = *(const short8*)(const void*)(hsrc + kt * 32);
    f32x4 acc0 = {0.f, 0.f, 0.f, 0.f};
    f32x4 acc1 = {0.f, 0.f, 0.f, 0.f};
#pragma unroll
    for (int kt = 0; kt < 16; kt++) {
      const int ks = ((kt << 2) + g4) ^ (b16 & 7);
      short8 a0 = *(const short8*)(Wl + b16 * 512 + (ks << 3));
      short8 a1 = *(const short8*)(Wl + (16 + b16) * 512 + (ks << 3));
      acc0 = __builtin_amdgcn_mfma_f32_16x16x32_bf16(a0, bfr[kt], acc0, 0, 0, 0);
      acc1 = __builtin_amdgcn_mfma_f32_16x16x32_bf16(a1, bfr[kt], acc1, 0, 0, 0);
    }
    // 4. pointwise (acc reg r = gate r: i,f,g,o; lane owns hcols hc0, hc0+1 of one batch)
    const float* xb = &xps[t & 1][batch * 36 + hc0];
    float2 xv0 = *(const float2*)(xb);
    float2 xv1 = *(const float2*)(xb + 8);
    float2 xv2 = *(const float2*)(xb + 16);
    float2 xv3 = *(const float2*)(xb + 24);
    float i0 = fsigmoid(acc0[0] + xv0.x);
    float ff0 = fsigmoid(acc0[1] + xv1.x);
    float g0 = ftanh(acc0[2] + xv2.x);
    float o0 = fsigmoid(acc0[3] + xv3.x);
    float i1 = fsigmoid(acc1[0] + xv0.y);
    float ff1 = fsigmoid(acc1[1] + xv1.y);
    float g1 = ftanh(acc1[2] + xv2.y);
    float o1 = fsigmoid(acc1[3] + xv3.y);
    c0 = ff0 * c0 + i0 * g0;
    c1 = ff1 * c1 + i1 * g1;
    h0 = o0 * ftanh(c0);
    h1 = o1 * ftanh(c1);
    // 5. stores: h_{t+1} (bf16 ping-pong) + outputs[t] (fp32)
    unsigned hb = (unsigned)(unsigned short)f2bf(h0) | ((unsigned)(unsigned short)f2bf(h1) << 16);
    *(unsigned*)(hbuf + (size_t)((t + 1) & 1) * (BB * HH) + (size_t)batch * HH + col) = hb;
    float2 ov; ov.x = h0; ov.y = h1;
    *(float2*)(outp + ((size_t)t * BB + batch) * HH + col) = ov;
    // 6/7. release: all block stores drained at barrier, then flag
    __syncthreads();
    if (tid == 0)
      __hip_atomic_store(flags + blk, (unsigned)(t + 1), __ATOMIC_RELEASE, __HIP_MEMORY_SCOPE_AGENT);
    // 8. commit prefetched xpart tile to LDS (other buffer; consumed after next sync)
    float* dst = &xps[(t + 1) & 1][xrow * 36 + xq * 8];
    if constexpr (sizeof(XT) == 4) {
      *(float4*)dst = pf0;
      *(float4*)(dst + 4) = pf1;
    } else {
#pragma unroll
      for (int j = 0; j < 8; j++) {
        union { unsigned short u; __half h; } cvu; cvu.u = (unsigned short)ph[j];
        dst[j] = __half2float(cvu.h);
      }
    }
  }
  // final (h_T, c_T)
  float* hT = outp + (size_t)TT * BB * HH;
  float* cT = hT + (size_t)BB * HH;
  float2 hv; hv.x = h0; hv.y = h1;
  float2 cv2; cv2.x = c0; cv2.y = c1;
  *(float2*)(hT + (size_t)batch * HH + col) = hv;
  *(float2*)(cT + (size_t)batch * HH + col) = cv2;
}

extern "C" void kernel_launch(void* const* d_in, const int* in_sizes, int n_in,
                              void* d_out, int out_size, void* d_ws, size_t ws_size,
                              hipStream_t stream) {
  (void)in_sizes; (void)n_in; (void)out_size;
  const float* x = (const float*)d_in[0];
  const float* Wih = (const float*)d_in[1];
  const float* Whh = (const float*)d_in[2];
  const float* bih = (const float*)d_in[3];
  const float* bhh = (const float*)d_in[4];
  float* outp = (float*)d_out;
  char* ws = (char*)d_ws;

  const size_t M = (size_t)TT * BB;  // 131072
  size_t off = 0;
  auto take = [&](size_t sz) { size_t r = off; off = (off + sz + 255) & ~255ULL; return r; };
  const size_t xbf_o = take(M * 512 * 2);
  const size_t wih_o = take((size_t)GG * 512 * 2);
  const size_t hbuf_o = take(2 * (size_t)BB * HH * 2);
  const size_t flg_o = take(64 * 4);
  const size_t xpart_o = off;
  const bool usef32 = (ws_size >= xpart_o + M * GG * 4);

  __hip_bfloat16* xbf = (__hip_bfloat16*)(ws + xbf_o);
  __hip_bfloat16* wihbf = (__hip_bfloat16*)(ws + wih_o);
  __hip_bfloat16* hbuf = (__hip_bfloat16*)(ws + hbuf_o);
  unsigned* flags = (unsigned*)(ws + flg_o);

  hipMemsetAsync(ws + hbuf_o, 0, 2 * (size_t)BB * HH * 2, stream);
  hipMemsetAsync(ws + flg_o, 0, 64 * 4, stream);

  cvt_bf16_kernel<<<4096, 256, 0, stream>>>((const float4*)x, (short4v*)xbf, (long)(M * 512 / 4));
  cvt_bf16_kernel<<<256, 256, 0, stream>>>((const float4*)Wih, (short4v*)wihbf, (long)((size_t)GG * 512 / 4));

  if (usef32) {
    float* xpart = (float*)(ws + xpart_o);
    gemm_xpart<float><<<16384, 256, 0, stream>>>(xbf, wihbf, bih, bhh, xpart);
    lstm_scan_kernel<float><<<64, 256, 0, stream>>>(xpart, Whh, hbuf, outp, flags);
  } else {
    __half* xpart = (__half*)(ws + xpart_o);
    gemm_xpart<__half><<<16384, 256, 0, stream>>>(xbf, wihbf, bih, bhh, xpart);
    lstm_scan_kernel<__half><<<64, 256, 0, stream>>>(xpart, Whh, hbuf, outp, flags);
  }
}